// Round 1
// baseline (14240.222 us; speedup 1.0000x reference)
//
#include <hip/hip_runtime.h>
#include <math.h>

#define E 768
#define NH 12
#define HD 64
#define TT 1024
#define BB 2
#define LL 6
#define VV 50257
#define FF 3072
#define MROWS (BB * TT)   // 2048

// ---------------- embedding: x[b,t,:] = wte[tok] + wpe[t] ----------------
__global__ void embed_kernel(const int* __restrict__ tokens,
                             const float* __restrict__ wte,
                             const float* __restrict__ wpe,
                             float* __restrict__ x) {
    int row = blockIdx.x;            // b*TT + t
    int t = row & (TT - 1);
    int tok = tokens[row];
    const float* src = wte + (size_t)tok * E;
    const float* pos = wpe + (size_t)t * E;
    float* dst = x + (size_t)row * E;
    for (int i = threadIdx.x; i < E; i += blockDim.x)
        dst[i] = src[i] + pos[i];
}

// ---------------- layernorm (one block per row of E=768) ----------------
__global__ void ln_kernel(const float* __restrict__ in,
                          const float* __restrict__ scale,
                          const float* __restrict__ bias,
                          float* __restrict__ out) {
    int row = blockIdx.x;
    const float* xr = in + (size_t)row * E;
    float s = 0.f, s2 = 0.f;
    float v[3];
    int j = 0;
    for (int i = threadIdx.x; i < E; i += 256, j++) {
        float t = xr[i];
        v[j] = t; s += t; s2 += t * t;
    }
    __shared__ float rs[4], rs2[4];
    for (int off = 32; off; off >>= 1) {
        s += __shfl_xor(s, off);
        s2 += __shfl_xor(s2, off);
    }
    int wave = threadIdx.x >> 6;
    if ((threadIdx.x & 63) == 0) { rs[wave] = s; rs2[wave] = s2; }
    __syncthreads();
    if (threadIdx.x == 0) {
        float a = 0.f, b = 0.f;
        for (int w = 0; w < 4; w++) { a += rs[w]; b += rs2[w]; }
        rs[0] = a; rs2[0] = b;
    }
    __syncthreads();
    float mu = rs[0] * (1.0f / E);
    float var = rs2[0] * (1.0f / E) - mu * mu;
    float r = rsqrtf(var + 1e-5f);
    float* orow = out + (size_t)row * E;
    j = 0;
    for (int i = threadIdx.x; i < E; i += 256, j++)
        orow[i] = (v[j] - mu) * r * scale[i] + bias[i];
}

// ---------------- GEMM C = A(MxK) @ W(KxN) [+bias][+gelu] ----------------
// Assumes M%64==0, N%64==0, K%16==0 (true for all in-block GEMMs).
__global__ void gemm_nn(const float* __restrict__ A, const float* __restrict__ W,
                        const float* __restrict__ bias, float* __restrict__ C,
                        int M, int N, int K, int act) {
    __shared__ float As[16][65];
    __shared__ float Bs[16][64];
    int tid = threadIdx.x;
    int tx = tid & 15, ty = tid >> 4;
    int m0 = blockIdx.y * 64, n0 = blockIdx.x * 64;
    float acc[4][4] = {};
    for (int k0 = 0; k0 < K; k0 += 16) {
        {
            int mm = tid >> 2, kq = (tid & 3) << 2;
            float4 av = *(const float4*)(A + (size_t)(m0 + mm) * K + k0 + kq);
            As[kq + 0][mm] = av.x; As[kq + 1][mm] = av.y;
            As[kq + 2][mm] = av.z; As[kq + 3][mm] = av.w;
        }
        {
            int kk = tid >> 4, nq = (tid & 15) << 2;
            float4 bv = *(const float4*)(W + (size_t)(k0 + kk) * N + n0 + nq);
            *(float4*)&Bs[kk][nq] = bv;
        }
        __syncthreads();
#pragma unroll
        for (int kk = 0; kk < 16; kk++) {
            float a[4], b[4];
#pragma unroll
            for (int i = 0; i < 4; i++) a[i] = As[kk][ty + 16 * i];
#pragma unroll
            for (int jj = 0; jj < 4; jj++) b[jj] = Bs[kk][tx + 16 * jj];
#pragma unroll
            for (int i = 0; i < 4; i++)
#pragma unroll
                for (int jj = 0; jj < 4; jj++) acc[i][jj] += a[i] * b[jj];
        }
        __syncthreads();
    }
#pragma unroll
    for (int i = 0; i < 4; i++) {
        int m = m0 + ty + 16 * i;
#pragma unroll
        for (int jj = 0; jj < 4; jj++) {
            int n = n0 + tx + 16 * jj;
            float v = acc[i][jj];
            if (bias) v += bias[n];
            if (act == 1) v = 0.5f * v * (1.0f + erff(v * 0.70710678118f));
            C[(size_t)m * N + n] = v;
        }
    }
}

// ---------------- GEMM C = A(MxK) @ Bt(NxK)^T  (logits) ----------------
__global__ void gemm_nt(const float* __restrict__ A, const float* __restrict__ Bt,
                        float* __restrict__ C, int M, int N, int K) {
    __shared__ float As[16][65];
    __shared__ float Bs[16][65];
    int tid = threadIdx.x;
    int tx = tid & 15, ty = tid >> 4;
    int m0 = blockIdx.y * 64, n0 = blockIdx.x * 64;
    float acc[4][4] = {};
    for (int k0 = 0; k0 < K; k0 += 16) {
        {
            int mm = tid >> 2, kq = (tid & 3) << 2;
            float4 av = *(const float4*)(A + (size_t)(m0 + mm) * K + k0 + kq);
            As[kq + 0][mm] = av.x; As[kq + 1][mm] = av.y;
            As[kq + 2][mm] = av.z; As[kq + 3][mm] = av.w;
        }
        {
            int nn = tid >> 2, kq = (tid & 3) << 2;
            int n = n0 + nn;
            float4 bv = make_float4(0.f, 0.f, 0.f, 0.f);
            if (n < N) bv = *(const float4*)(Bt + (size_t)n * K + k0 + kq);
            Bs[kq + 0][nn] = bv.x; Bs[kq + 1][nn] = bv.y;
            Bs[kq + 2][nn] = bv.z; Bs[kq + 3][nn] = bv.w;
        }
        __syncthreads();
#pragma unroll
        for (int kk = 0; kk < 16; kk++) {
            float a[4], b[4];
#pragma unroll
            for (int i = 0; i < 4; i++) a[i] = As[kk][ty + 16 * i];
#pragma unroll
            for (int jj = 0; jj < 4; jj++) b[jj] = Bs[kk][tx + 16 * jj];
#pragma unroll
            for (int i = 0; i < 4; i++)
#pragma unroll
                for (int jj = 0; jj < 4; jj++) acc[i][jj] += a[i] * b[jj];
        }
        __syncthreads();
    }
#pragma unroll
    for (int i = 0; i < 4; i++) {
        int m = m0 + ty + 16 * i;
#pragma unroll
        for (int jj = 0; jj < 4; jj++) {
            int n = n0 + tx + 16 * jj;
            if (n < N) C[(size_t)m * N + n] = acc[i][jj];
        }
    }
}

// ---------------- flash-style causal attention ----------------
// one wave (64 threads) per (b, h, tq); lane = head dim
__global__ void attn_kernel(const float* __restrict__ q,
                            const float* __restrict__ k,
                            const float* __restrict__ v,
                            float* __restrict__ o) {
    int idx = blockIdx.x;
    int tq = idx & (TT - 1);
    int h = (idx >> 10) % NH;
    int b = idx / (TT * NH);
    int lane = threadIdx.x;
    size_t rowq = ((size_t)(b * TT + tq)) * E + h * HD;
    float qd = q[rowq + lane] * 0.125f;  // 1/sqrt(64)
    float m = -INFINITY, l = 0.f, acc = 0.f;
    size_t base = ((size_t)b * TT) * E + h * HD;
    for (int tk = 0; tk <= tq; tk++) {
        size_t rk = base + (size_t)tk * E;
        float s = qd * k[rk + lane];
        for (int off = 32; off; off >>= 1) s += __shfl_xor(s, off);
        float mn = fmaxf(m, s);
        float corr = __expf(m - mn);
        float p = __expf(s - mn);
        l = l * corr + p;
        acc = acc * corr + p * v[rk + lane];
        m = mn;
    }
    o[rowq + lane] = acc / l;
}

// ---------------- residual add (float4) ----------------
__global__ void add_kernel(float* __restrict__ x, const float* __restrict__ y, int n4) {
    int i = blockIdx.x * blockDim.x + threadIdx.x;
    if (i < n4) {
        float4 a = ((float4*)x)[i];
        float4 b = ((const float4*)y)[i];
        a.x += b.x; a.y += b.y; a.z += b.z; a.w += b.w;
        ((float4*)x)[i] = a;
    }
}

extern "C" void kernel_launch(void* const* d_in, const int* in_sizes, int n_in,
                              void* d_out, int out_size, void* d_ws, size_t ws_size,
                              hipStream_t stream) {
    const int*   tokens = (const int*)d_in[0];
    const float* wte   = (const float*)d_in[1];
    const float* wpe   = (const float*)d_in[2];
    const float* Wq    = (const float*)d_in[3];
    const float* Wk    = (const float*)d_in[4];
    const float* Wv    = (const float*)d_in[5];
    const float* Wo    = (const float*)d_in[6];
    const float* bo    = (const float*)d_in[7];
    const float* ln1_s = (const float*)d_in[8];
    const float* ln1_b = (const float*)d_in[9];
    const float* W1    = (const float*)d_in[10];
    const float* b1    = (const float*)d_in[11];
    const float* W2    = (const float*)d_in[12];
    const float* b2    = (const float*)d_in[13];
    const float* ln2_s = (const float*)d_in[14];
    const float* ln2_b = (const float*)d_in[15];
    const float* lnf_s = (const float*)d_in[16];
    const float* lnf_b = (const float*)d_in[17];
    float* out = (float*)d_out;

    const size_t NE = (size_t)MROWS * E;   // 2048*768
    float* ws = (float*)d_ws;
    float* x  = ws;
    float* h  = x + NE;
    float* qb = h + NE;
    float* kb = qb + NE;
    float* vb = kb + NE;
    float* ob = vb + NE;
    float* mid = out;                      // 2048*3072 scratch at head of d_out

    const int n4 = (int)(NE / 4);
    dim3 gE(E / 64, MROWS / 64);           // (12, 32)
    dim3 gF(FF / 64, MROWS / 64);          // (48, 32)

    embed_kernel<<<MROWS, 256, 0, stream>>>(tokens, wte, wpe, x);

    for (int l = 0; l < LL; l++) {
        const float* wq = Wq + (size_t)l * E * E;
        const float* wk = Wk + (size_t)l * E * E;
        const float* wv = Wv + (size_t)l * E * E;
        const float* wo = Wo + (size_t)l * E * E;
        const float* bo_l = bo + (size_t)l * E;
        const float* w1 = W1 + (size_t)l * E * FF;
        const float* b1_l = b1 + (size_t)l * FF;
        const float* w2 = W2 + (size_t)l * FF * E;
        const float* b2_l = b2 + (size_t)l * E;

        ln_kernel<<<MROWS, 256, 0, stream>>>(x, ln1_s + (size_t)l * E, ln1_b + (size_t)l * E, h);
        gemm_nn<<<gE, 256, 0, stream>>>(h, wq, nullptr, qb, MROWS, E, E, 0);
        gemm_nn<<<gE, 256, 0, stream>>>(h, wk, nullptr, kb, MROWS, E, E, 0);
        gemm_nn<<<gE, 256, 0, stream>>>(h, wv, nullptr, vb, MROWS, E, E, 0);
        attn_kernel<<<BB * NH * TT, 64, 0, stream>>>(qb, kb, vb, ob);
        gemm_nn<<<gE, 256, 0, stream>>>(ob, wo, bo_l, h, MROWS, E, E, 0);
        add_kernel<<<(n4 + 255) / 256, 256, 0, stream>>>(x, h, n4);
        ln_kernel<<<MROWS, 256, 0, stream>>>(x, ln2_s + (size_t)l * E, ln2_b + (size_t)l * E, h);
        gemm_nn<<<gF, 256, 0, stream>>>(h, w1, b1_l, mid, MROWS, FF, E, 1);
        gemm_nn<<<gE, 256, 0, stream>>>(mid, w2, b2_l, h, MROWS, E, FF, 0);
        add_kernel<<<(n4 + 255) / 256, 256, 0, stream>>>(x, h, n4);
    }

    ln_kernel<<<MROWS, 256, 0, stream>>>(x, lnf_s, lnf_b, h);
    dim3 gL((VV + 63) / 64, MROWS / 64);   // (786, 32)
    gemm_nt<<<gL, 256, 0, stream>>>(h, wte, out, MROWS, VV, E);
}